// Round 12
// baseline (129.137 us; speedup 1.0000x reference)
//
#include <hip/hip_runtime.h>
#include <math.h>

#define NB 2
#define NQ 16384        // 32*512 downsampled points per batch
#define IN_H 64
#define IN_W 2048
#define BIG 1e30f
#define NQT (NB * NQ)
#define NG 4            // target groups (quarters)
#define NP (NG * 3)     // partial planes

typedef __bf16 bf16x8 __attribute__((ext_vector_type(8)));
typedef float f32x16 __attribute__((ext_vector_type(16)));

__device__ inline float med3(float a, float b, float c) {
    return __builtin_amdgcn_fmed3f(a, b, c);
}
// branchless sorted-insert of v into b0<=b1<=b2 (3 VALU)
#define INSERT3(B0, B1, B2, V)                    \
    do { float _v = (V);                          \
         (B2) = med3((B1), (B2), _v);             \
         (B1) = med3((B0), (B1), _v);             \
         (B0) = fminf((B0), _v); } while (0)

union PK { __bf16 h[8]; uint4 u; };

// ---------------------------------------------------------------------------
// pack_kernel: (a) bf16 compensated A-fragments for mfma_f32_32x32x16_bf16,
// (b) compact fp32 float4 (x,y,z,||t||^2) per target for the exact pass-2
// recompute. Also zeroes ALL control words (accum, done, 256 per-group
// qcnt) — ws contents are not trusted across iterations.
// ---------------------------------------------------------------------------
__global__ __launch_bounds__(256) void pack_kernel(
    const float* __restrict__ tgt_pc,   // [B,3,64,2048]
    uint4* __restrict__ packed,
    float4* __restrict__ tgt4,
    float* __restrict__ zws)
{
    if (blockIdx.x == 0) {
        zws[threadIdx.x] = 0.f;                 // bytes 0..1024
        if (threadIdx.x < 32) zws[256 + threadIdx.x] = 0.f;  // ..1152
    }

    int gid = blockIdx.x * 256 + threadIdx.x;   // [0, NB*NQ)
    int b = gid >> 14, t = gid & (NQ - 1);
    int oh = t >> 9, ow = t & 511;
    const size_t PL = (size_t)IN_H * IN_W;
    size_t base = ((size_t)(b * 3) * IN_H + oh * 2) * IN_W + ow * 4;
    float x = tgt_pc[base], y = tgt_pc[base + PL], z = tgt_pc[base + 2 * PL];
    bool valid = (x != 0.f) || (y != 0.f) || (z != 0.f);
    float ntx = x * x + y * y + z * z;
    float nt = valid ? ntx : BIG;               // pass-1 sentinel
    float tx = valid ? -2.f * x : 0.f;
    float ty = valid ? -2.f * y : 0.f;
    float tz = valid ? -2.f * z : 0.f;

    __bf16 txh = (__bf16)tx, tyh = (__bf16)ty, tzh = (__bf16)tz;
    __bf16 txl = (__bf16)(tx - (float)txh);
    __bf16 tyl = (__bf16)(ty - (float)tyh);
    __bf16 tzl = (__bf16)(tz - (float)tzh);
    __bf16 nth = (__bf16)nt;
    __bf16 ntl = (__bf16)(nt - (float)nth);

    PK h0, h1;
    h0.h[0] = txh; h0.h[1] = tyh; h0.h[2] = tzh; h0.h[3] = txh;
    h0.h[4] = tyh; h0.h[5] = tzh; h0.h[6] = txl; h0.h[7] = tyl;
    h1.h[0] = tzl; h1.h[1] = nth; h1.h[2] = ntl; h1.h[3] = (__bf16)1.0f;
    h1.h[4] = (__bf16)1.0f; h1.h[5] = (__bf16)0.0f;
    h1.h[6] = (__bf16)0.0f; h1.h[7] = (__bf16)0.0f;

    int tile = t >> 5, m = t & 31;
    size_t o = (size_t)(b * 512 + tile) * 64 + m;   // uint4 units
    packed[o]      = h0.u;   // k0..7
    packed[o + 32] = h1.u;   // k8..15

    // exact-recompute buffer: raw xyz (zeroed if invalid), w = nt or 1e20
    tgt4[gid] = make_float4(valid ? x : 0.f, valid ? y : 0.f,
                            valid ? z : 0.f, valid ? ntx : 1e20f);
}

// ---------------------------------------------------------------------------
// knn_merge (R12): R5's proven pass-1/pass-2 VERBATIM (best measured, 51us),
// plus the merge fused in via a last-finisher protocol — R11 post-mortem:
// hipLaunchCooperativeKernel silently failed (out never written), so the
// grid-barrier route is out; but knn->merge is a REDUCTION and needs no
// barrier: the 4 quarter-blocks of group (b,qt) bump qcnt[b*128+qt]; the
// last one (atomicAdd old==3) merges the group's 128 queries in-kernel.
// Ordering: __syncthreads (block stores drained to L2) -> tid0
// __threadfence (L2 -> coherent point) -> atomicAdd publish; the reader's
// partial loads are first-touch clean misses -> fresh data. Final scalar
// keeps the proven done/accum atomic protocol (256 events).
// This removes one of three dispatches; the ~58us constant (total-knn) gap
// has been the dominant cost since R0.
// ---------------------------------------------------------------------------
#define COMPUTE_TILE(U, IDX)                                                  \
    do {                                                                      \
        bf16x8 af = __builtin_bit_cast(bf16x8, (U));                          \
        f32x16 d = __builtin_amdgcn_mfma_f32_32x32x16_bf16(af, bq, zero, 0, 0, 0); \
        float m0 = fminf(fminf(d[0], d[1]), fminf(d[2], d[3]));               \
        float m1 = fminf(fminf(d[4], d[5]), fminf(d[6], d[7]));               \
        float m2 = fminf(fminf(d[8], d[9]), fminf(d[10], d[11]));             \
        float m3 = fminf(fminf(d[12], d[13]), fminf(d[14], d[15]));           \
        float m = fminf(fminf(m0, m1), fminf(m2, m3));                        \
        unsigned u = (__float_as_uint(m) & ~127u) | (unsigned)(IDX);          \
        float pv = __uint_as_float(u);                                        \
        if ((IDX) & 1) { INSERT3(c0b, c1b, c2b, pv); }                        \
        else           { INSERT3(c0a, c1a, c2a, pv); }                        \
    } while (0)

__global__ __launch_bounds__(256, 4) void knn_merge(
    const float* __restrict__ src_pc,   // [B,64,2048,3]
    const uint4* __restrict__ packed,
    const float4* __restrict__ tgt4,
    float* __restrict__ partial,        // [NG][3][NQT] plane-major
    float* __restrict__ accum,          // {sum0,cnt0,sum1,cnt1}
    int* __restrict__ qcnt,             // [NB*128] per-group counters
    int* __restrict__ done_cnt,
    float* __restrict__ out)
{
    const int tid = threadIdx.x;
    const int lane = tid & 63;
    const int w = tid >> 6;
    int blk = blockIdx.x;
    int qt = blk & 127;
    int quarter = (blk >> 7) & 3;
    int b = blk >> 9;

    // ---- query-side B fragment (k = (lane>>5)*8 + j, col n = lane&31) ----
    int n = lane & 31;
    int q = qt * 128 + w * 32 + n;
    size_t sbase = (((size_t)b * IN_H + (q >> 9) * 2) * IN_W + (q & 511) * 4) * 3;
    float sx = src_pc[sbase], sy = src_pc[sbase + 1], sz = src_pc[sbase + 2];
    float ns = sx * sx + sy * sy + sz * sz;
    __bf16 sxh = (__bf16)sx, syh = (__bf16)sy, szh = (__bf16)sz;
    __bf16 sxl = (__bf16)(sx - (float)sxh);
    __bf16 syl = (__bf16)(sy - (float)syh);
    __bf16 szl = (__bf16)(sz - (float)szh);
    __bf16 nsh = (__bf16)ns;
    __bf16 nsl = (__bf16)(ns - (float)nsh);
    bf16x8 bq;
    if ((lane >> 5) == 0) {
        bq[0] = sxh; bq[1] = syh; bq[2] = szh; bq[3] = sxl;
        bq[4] = syl; bq[5] = szl; bq[6] = sxh; bq[7] = syh;
    } else {
        bq[0] = szh; bq[1] = (__bf16)1.0f; bq[2] = (__bf16)1.0f; bq[3] = nsh;
        bq[4] = nsl; bq[5] = (__bf16)0.0f; bq[6] = (__bf16)0.0f; bq[7] = (__bf16)0.0f;
    }

    f32x16 zero;
    #pragma unroll
    for (int i = 0; i < 16; ++i) zero[i] = 0.f;

    // two independent packed (min | tile-idx) top-3 chains (even/odd tiles)
    float c0a = BIG, c1a = BIG, c2a = BIG;
    float c0b = BIG, c1b = BIG, c2b = BIG;

    const uint4* pkq = packed + (size_t)b * 32768 + (size_t)quarter * 8192 + lane;

    // ---- pass 1: 128 tiles, fully unrolled, 4-tile ping-pong pipeline ----
    uint4 bufA4[4], bufB4[4];
    #pragma unroll
    for (int i = 0; i < 4; ++i) bufA4[i] = pkq[i * 64];     // tiles 0..3

    #pragma unroll
    for (int gg = 0; gg < 16; ++gg) {
        #pragma unroll
        for (int i = 0; i < 4; ++i) bufB4[i] = pkq[((2 * gg + 1) * 4 + i) * 64];
        #pragma unroll
        for (int i = 0; i < 4; ++i) COMPUTE_TILE(bufA4[i], 8 * gg + i);
        if (gg < 15) {
            #pragma unroll
            for (int i = 0; i < 4; ++i) bufA4[i] = pkq[((2 * gg + 2) * 4 + i) * 64];
        }
        #pragma unroll
        for (int i = 0; i < 4; ++i) COMPUTE_TILE(bufB4[i], 8 * gg + 4 + i);
    }

    // exact merge of the two chains: top3(A u B) from top3(A), top3(B)
    INSERT3(c0a, c1a, c2a, c0b);
    INSERT3(c0a, c1a, c2a, c1b);
    INSERT3(c0a, c1a, c2a, c2b);

    // ---- pass 2: exact fp32 recompute of the 3 candidate tiles ----
    int half = lane >> 5;
    int ti[3] = { (int)(__float_as_uint(c0a) & 127u),
                  (int)(__float_as_uint(c1a) & 127u),
                  (int)(__float_as_uint(c2a) & 127u) };
    float e0 = BIG, e1 = BIG, e2 = BIG;
    const float4* t4b = tgt4 + (size_t)b * NQ + (size_t)quarter * 4096;
    #pragma unroll
    for (int i = 0; i < 3; ++i) {
        int tbase = ti[i] * 32 + 4 * half;
        #pragma unroll
        for (int rr = 0; rr < 16; ++rr) {
            int row = (rr & 3) + 8 * (rr >> 2);     // + 4*half folded in tbase
            float4 t4 = t4b[tbase + row];
            float dot = sx * t4.x;
            dot = fmaf(sy, t4.y, dot);
            dot = fmaf(sz, t4.z, dot);
            float d2 = fmaf(-2.f, dot, ns + t4.w);  // exact-form d^2
            INSERT3(e0, e1, e2, d2);
        }
    }

    // ---- merge lane halves (L <- L+32, same query col), write planes ----
    float f0 = __shfl_down(e0, 32, 64);
    float f1 = __shfl_down(e1, 32, 64);
    float f2 = __shfl_down(e2, 32, 64);
    if (lane < 32) {
        INSERT3(e0, e1, e2, f0);
        INSERT3(e0, e1, e2, f1);
        INSERT3(e0, e1, e2, f2);
        int gq = b * NQ + q;
        partial[(quarter * 3 + 0) * NQT + gq] = e0;
        partial[(quarter * 3 + 1) * NQT + gq] = e1;
        partial[(quarter * 3 + 2) * NQT + gq] = e2;
    }

    // ---- fused merge: last of the group's 4 quarter-blocks does it ------
    __shared__ int do_merge;
    __syncthreads();                    // all block stores drained (vmcnt)
    if (tid == 0) {
        __threadfence();                // L2 -> coherent point (release)
        int old = atomicAdd(&qcnt[b * 128 + qt], 1);
        do_merge = (old == NG - 1) ? 1 : 0;
    }
    __syncthreads();

    if (do_merge) {
        float dsum = 0.f, wt = 0.f;
        if (tid < 128) {
            int qq = qt * 128 + tid;
            int gq = b * NQ + qq;
            float b0 = BIG, b1 = BIG, b2 = BIG;
            #pragma unroll
            for (int c = 0; c < NP; ++c) {
                float v = partial[c * NQT + gq];
                INSERT3(b0, b1, b2, v);
            }
            size_t sb2 = (((size_t)b * IN_H + (qq >> 9) * 2) * IN_W
                          + (qq & 511) * 4) * 3;
            float x = src_pc[sb2], y = src_pc[sb2 + 1], z = src_pc[sb2 + 2];
            wt = ((x != 0.f) || (y != 0.f) || (z != 0.f)) ? 1.f : 0.f;
            float d = fminf(sqrtf(fmaxf(b0, 0.f)), 1e10f)
                    + fminf(sqrtf(fmaxf(b1, 0.f)), 1e10f)
                    + fminf(sqrtf(fmaxf(b2, 0.f)), 1e10f);
            dsum = d * wt;
        }
        #pragma unroll
        for (int off = 32; off > 0; off >>= 1) {
            dsum += __shfl_down(dsum, off, 64);
            wt   += __shfl_down(wt, off, 64);
        }
        __shared__ float sd[4], sw4[4];
        if (lane == 0) { sd[w] = dsum; sw4[w] = wt; }
        __syncthreads();
        if (tid == 0) {
            atomicAdd(&accum[b * 2 + 0], sd[0] + sd[1] + sd[2] + sd[3]);
            atomicAdd(&accum[b * 2 + 1], sw4[0] + sw4[1] + sw4[2] + sw4[3]);
            __threadfence();
            int dd = atomicAdd(done_cnt, 1);
            if (dd == NB * 128 - 1) {       // all 256 group-merges done
                float s0 = atomicAdd(&accum[0], 0.f);
                float c0 = atomicAdd(&accum[1], 0.f);
                float s1 = atomicAdd(&accum[2], 0.f);
                float c1 = atomicAdd(&accum[3], 0.f);
                float r = s0 / (3.0f * fmaxf(c0, 1.0f))
                        + s1 / (3.0f * fmaxf(c1, 1.0f));
                out[0] = r / (float)NB;
            }
        }
    }
}

// ---------------------------------------------------------------------------
extern "C" void kernel_launch(void* const* d_in, const int* in_sizes, int n_in,
                              void* d_out, int out_size, void* d_ws, size_t ws_size,
                              hipStream_t stream) {
    const float* src_pc = (const float*)d_in[0];   // [2,64,2048,3]
    const float* tgt_pc = (const float*)d_in[1];   // [2,3,64,2048]
    float* out = (float*)d_out;

    char* ws = (char*)d_ws;
    float*  accum   = (float*)ws;                   // 4 floats @ 0
    int*    done    = (int*)(ws + 32);              // 1 int    @ 32
    int*    qcnt    = (int*)(ws + 64);              // 256 ints @ 64..1088
    float*  partial = (float*)(ws + 4096);          // 12 planes = 1.5 MB
    uint4*  packed  = (uint4*)(ws + 2097152);       // 1 MB
    float4* tgt4    = (float4*)(ws + 3145728);      // 512 KB

    pack_kernel<<<NQT / 256, 256, 0, stream>>>(tgt_pc, packed, tgt4, (float*)ws);
    knn_merge<<<NB * NG * 128, 256, 0, stream>>>(src_pc, packed, tgt4,
                                                 partial, accum, qcnt, done, out);
}

// Round 13
// 110.071 us; speedup vs baseline: 1.1732x; 1.1732x over previous
//
#include <hip/hip_runtime.h>
#include <math.h>

#define NB 2
#define NQ 16384        // 32*512 downsampled points per batch
#define IN_H 64
#define IN_W 2048
#define BIG 1e30f
#define NQT (NB * NQ)
#define NG 4            // target groups (quarters)
#define NP (NG * 3)     // partial planes

typedef __bf16 bf16x8 __attribute__((ext_vector_type(8)));
typedef float f32x16 __attribute__((ext_vector_type(16)));

__device__ inline float med3(float a, float b, float c) {
    return __builtin_amdgcn_fmed3f(a, b, c);
}
// branchless sorted-insert of v into b0<=b1<=b2 (3 VALU)
#define INSERT3(B0, B1, B2, V)                    \
    do { float _v = (V);                          \
         (B2) = med3((B1), (B2), _v);             \
         (B1) = med3((B0), (B1), _v);             \
         (B0) = fminf((B0), _v); } while (0)

union PK { __bf16 h[8]; uint4 u; };

// ---------------------------------------------------------------------------
// pack_kernel: (a) bf16 compensated A-fragments for mfma_f32_32x32x16_bf16
// (layout verified, absmax 0.0), (b) compact fp32 float4 (x,y,z,||t||^2)
// per target for the exact pass-2 recompute (invalid -> xyz=0, w=1e20 so
// sqrt=1e10, matching the reference's INVALID_DIST). Also zeroes accum/done.
// ---------------------------------------------------------------------------
__global__ __launch_bounds__(256) void pack_kernel(
    const float* __restrict__ tgt_pc,   // [B,3,64,2048]
    uint4* __restrict__ packed,
    float4* __restrict__ tgt4,
    float* __restrict__ zws)
{
    if (blockIdx.x == 0 && threadIdx.x < 16) zws[threadIdx.x] = 0.f;

    int gid = blockIdx.x * 256 + threadIdx.x;   // [0, NB*NQ)
    int b = gid >> 14, t = gid & (NQ - 1);
    int oh = t >> 9, ow = t & 511;
    const size_t PL = (size_t)IN_H * IN_W;
    size_t base = ((size_t)(b * 3) * IN_H + oh * 2) * IN_W + ow * 4;
    float x = tgt_pc[base], y = tgt_pc[base + PL], z = tgt_pc[base + 2 * PL];
    bool valid = (x != 0.f) || (y != 0.f) || (z != 0.f);
    float ntx = x * x + y * y + z * z;
    float nt = valid ? ntx : BIG;               // pass-1 sentinel
    float tx = valid ? -2.f * x : 0.f;
    float ty = valid ? -2.f * y : 0.f;
    float tz = valid ? -2.f * z : 0.f;

    __bf16 txh = (__bf16)tx, tyh = (__bf16)ty, tzh = (__bf16)tz;
    __bf16 txl = (__bf16)(tx - (float)txh);
    __bf16 tyl = (__bf16)(ty - (float)tyh);
    __bf16 tzl = (__bf16)(tz - (float)tzh);
    __bf16 nth = (__bf16)nt;
    __bf16 ntl = (__bf16)(nt - (float)nth);

    PK h0, h1;
    h0.h[0] = txh; h0.h[1] = tyh; h0.h[2] = tzh; h0.h[3] = txh;
    h0.h[4] = tyh; h0.h[5] = tzh; h0.h[6] = txl; h0.h[7] = tyl;
    h1.h[0] = tzl; h1.h[1] = nth; h1.h[2] = ntl; h1.h[3] = (__bf16)1.0f;
    h1.h[4] = (__bf16)1.0f; h1.h[5] = (__bf16)0.0f;
    h1.h[6] = (__bf16)0.0f; h1.h[7] = (__bf16)0.0f;

    int tile = t >> 5, m = t & 31;
    size_t o = (size_t)(b * 512 + tile) * 64 + m;   // uint4 units
    packed[o]      = h0.u;   // k0..7
    packed[o + 32] = h1.u;   // k8..15

    // exact-recompute buffer: raw xyz (zeroed if invalid), w = nt or 1e20
    tgt4[gid] = make_float4(valid ? x : 0.f, valid ? y : 0.f,
                            valid ? z : 0.f, valid ? ntx : 1e20f);
}

// ---------------------------------------------------------------------------
// knn_mfma (R13): R5 verbatim (best measured, 51us: no LDS/barriers, wave
// scans its quarter's 128 tiles, 8+8 ping-pong, builtin MFMA) + WAVE-PHASE
// ROTATION. R12 post-mortem: fusion is net-negative (per-block threadfence
// +30us); the residual ~48us gap is harness reset dispatches (fixed). R5
// issue accounting: ~124 cyc/tile issued vs 240 elapsed — all 4 waves run
// the IDENTICAL instruction stream on IDENTICAL addresses (pkq has no w),
// so their s_waitcnt windows coincide and the SIMD drains at every group
// boundary. Fix: wave w starts its circular tile scan at offset 2*w
// (&127 wrap, SALU-only via readfirstlane) — load-wait windows shift by
// ~2 tile-times (> the wait length) while streams stay within 2KB for
// L1/L2 temporal reuse. Pack parity keyed on compile-time J; packed idx
// carries the REAL tile T for pass-2.
// ---------------------------------------------------------------------------
#define COMPUTE_TILE(U, TI, PAR)                                              \
    do {                                                                      \
        bf16x8 af = __builtin_bit_cast(bf16x8, (U));                          \
        f32x16 d = __builtin_amdgcn_mfma_f32_32x32x16_bf16(af, bq, zero, 0, 0, 0); \
        float m0 = fminf(fminf(d[0], d[1]), fminf(d[2], d[3]));               \
        float m1 = fminf(fminf(d[4], d[5]), fminf(d[6], d[7]));               \
        float m2 = fminf(fminf(d[8], d[9]), fminf(d[10], d[11]));             \
        float m3 = fminf(fminf(d[12], d[13]), fminf(d[14], d[15]));           \
        float m = fminf(fminf(m0, m1), fminf(m2, m3));                        \
        unsigned u = (__float_as_uint(m) & ~127u) | (unsigned)(TI);           \
        float pv = __uint_as_float(u);                                        \
        if ((PAR) & 1) { INSERT3(c0b, c1b, c2b, pv); }                        \
        else           { INSERT3(c0a, c1a, c2a, pv); }                        \
    } while (0)

__global__ __launch_bounds__(256, 4) void knn_mfma(
    const float* __restrict__ src_pc,   // [B,64,2048,3]
    const uint4* __restrict__ packed,
    const float4* __restrict__ tgt4,
    float* __restrict__ partial)        // [NG][3][NQT] plane-major
{
    const int tid = threadIdx.x;
    const int lane = tid & 63;
    const int w = tid >> 6;
    int blk = blockIdx.x;
    int qt = blk & 127;
    int quarter = (blk >> 7) & 3;
    int b = blk >> 9;

    // ---- query-side B fragment (k = (lane>>5)*8 + j, col n = lane&31) ----
    int n = lane & 31;
    int q = qt * 128 + w * 32 + n;
    size_t sbase = (((size_t)b * IN_H + (q >> 9) * 2) * IN_W + (q & 511) * 4) * 3;
    float sx = src_pc[sbase], sy = src_pc[sbase + 1], sz = src_pc[sbase + 2];
    float ns = sx * sx + sy * sy + sz * sz;
    __bf16 sxh = (__bf16)sx, syh = (__bf16)sy, szh = (__bf16)sz;
    __bf16 sxl = (__bf16)(sx - (float)sxh);
    __bf16 syl = (__bf16)(sy - (float)syh);
    __bf16 szl = (__bf16)(sz - (float)szh);
    __bf16 nsh = (__bf16)ns;
    __bf16 nsl = (__bf16)(ns - (float)nsh);
    bf16x8 bq;
    if ((lane >> 5) == 0) {
        bq[0] = sxh; bq[1] = syh; bq[2] = szh; bq[3] = sxl;
        bq[4] = syl; bq[5] = szl; bq[6] = sxh; bq[7] = syh;
    } else {
        bq[0] = szh; bq[1] = (__bf16)1.0f; bq[2] = (__bf16)1.0f; bq[3] = nsh;
        bq[4] = nsl; bq[5] = (__bf16)0.0f; bq[6] = (__bf16)0.0f; bq[7] = (__bf16)0.0f;
    }

    f32x16 zero;
    #pragma unroll
    for (int i = 0; i < 16; ++i) zero[i] = 0.f;

    // two independent packed (min | tile-idx) top-3 chains (even/odd J)
    float c0a = BIG, c1a = BIG, c2a = BIG;
    float c0b = BIG, c1b = BIG, c2b = BIG;

    const uint4* pkq = packed + (size_t)b * 32768 + (size_t)quarter * 8192 + lane;

    // wave id in an SGPR (readfirstlane) so the rotation math stays SALU
    int wsid = __builtin_amdgcn_readfirstlane(tid) >> 6;
    int rot = wsid * 2;                 // stagger waves by 2 tiles

    // ---- pass 1: 128 tiles, rotated circular order, 8+8 ping-pong -------
    uint4 bufA[8], bufB[8];
    #pragma unroll
    for (int i = 0; i < 8; ++i) bufA[i] = pkq[((i + rot) & 127) * 64];

    #pragma unroll
    for (int gg = 0; gg < 8; ++gg) {
        #pragma unroll
        for (int i = 0; i < 8; ++i)
            bufB[i] = pkq[((((2 * gg + 1) * 8 + i) + rot) & 127) * 64];
        #pragma unroll
        for (int i = 0; i < 8; ++i) {
            const int J = 2 * gg * 8 + i;
            COMPUTE_TILE(bufA[i], (J + rot) & 127, J);
        }
        if (gg < 7) {
            #pragma unroll
            for (int i = 0; i < 8; ++i)
                bufA[i] = pkq[((((2 * gg + 2) * 8 + i) + rot) & 127) * 64];
        }
        #pragma unroll
        for (int i = 0; i < 8; ++i) {
            const int J = (2 * gg + 1) * 8 + i;
            COMPUTE_TILE(bufB[i], (J + rot) & 127, J);
        }
    }

    // exact merge of the two chains: top3(A u B) from top3(A), top3(B)
    INSERT3(c0a, c1a, c2a, c0b);
    INSERT3(c0a, c1a, c2a, c1b);
    INSERT3(c0a, c1a, c2a, c2b);

    // ---- pass 2: exact fp32 recompute of the 3 candidate tiles ----
    int half = lane >> 5;
    int ti[3] = { (int)(__float_as_uint(c0a) & 127u),
                  (int)(__float_as_uint(c1a) & 127u),
                  (int)(__float_as_uint(c2a) & 127u) };
    float e0 = BIG, e1 = BIG, e2 = BIG;
    const float4* t4b = tgt4 + (size_t)b * NQ + (size_t)quarter * 4096;
    #pragma unroll
    for (int i = 0; i < 3; ++i) {
        int tbase = ti[i] * 32 + 4 * half;
        #pragma unroll
        for (int rr = 0; rr < 16; ++rr) {
            int row = (rr & 3) + 8 * (rr >> 2);     // + 4*half folded in tbase
            float4 t4 = t4b[tbase + row];
            float dot = sx * t4.x;
            dot = fmaf(sy, t4.y, dot);
            dot = fmaf(sz, t4.z, dot);
            float d2 = fmaf(-2.f, dot, ns + t4.w);  // exact-form d^2
            INSERT3(e0, e1, e2, d2);
        }
    }

    // ---- merge lane halves (L <- L+32, same query col), write planes ----
    float f0 = __shfl_down(e0, 32, 64);
    float f1 = __shfl_down(e1, 32, 64);
    float f2 = __shfl_down(e2, 32, 64);
    if (lane < 32) {
        INSERT3(e0, e1, e2, f0);
        INSERT3(e0, e1, e2, f1);
        INSERT3(e0, e1, e2, f2);
        int gq = b * NQ + q;
        partial[(quarter * 3 + 0) * NQT + gq] = e0;
        partial[(quarter * 3 + 1) * NQT + gq] = e1;
        partial[(quarter * 3 + 2) * NQT + gq] = e2;
    }
}

// ---------------------------------------------------------------------------
// merge_final: per query merge 4 quarter-trios, sqrt+clamp, masked reduce,
// per-batch atomics; last finished block computes the scalar output.
// ---------------------------------------------------------------------------
__global__ __launch_bounds__(256) void merge_final(
    const float* __restrict__ partial,
    const float* __restrict__ src_pc,
    float* __restrict__ accum,          // {sum0,cnt0,sum1,cnt1}
    int* __restrict__ done_cnt,
    float* __restrict__ out)
{
    int gid = blockIdx.x * 256 + threadIdx.x;   // < NQT
    int b = gid >> 14;
    int q = gid & (NQ - 1);

    float b0 = BIG, b1 = BIG, b2 = BIG;
    #pragma unroll
    for (int c = 0; c < NP; ++c) {
        float v = partial[c * NQT + gid];       // coalesced plane reads
        INSERT3(b0, b1, b2, v);
    }

    size_t base = (((size_t)b * IN_H + (q >> 9) * 2) * IN_W + (q & 511) * 4) * 3;
    float x = src_pc[base], y = src_pc[base + 1], z = src_pc[base + 2];
    float wt = ((x != 0.f) || (y != 0.f) || (z != 0.f)) ? 1.f : 0.f;

    float d = fminf(sqrtf(fmaxf(b0, 0.f)), 1e10f)
            + fminf(sqrtf(fmaxf(b1, 0.f)), 1e10f)
            + fminf(sqrtf(fmaxf(b2, 0.f)), 1e10f);
    float dsum = d * wt;

    #pragma unroll
    for (int off = 32; off > 0; off >>= 1) {
        dsum += __shfl_down(dsum, off, 64);
        wt   += __shfl_down(wt, off, 64);
    }
    __shared__ float sd[4], sw4[4];
    int lane = threadIdx.x & 63, wv = threadIdx.x >> 6;
    if (lane == 0) { sd[wv] = dsum; sw4[wv] = wt; }
    __syncthreads();
    if (threadIdx.x == 0) {
        atomicAdd(&accum[b * 2 + 0], sd[0] + sd[1] + sd[2] + sd[3]);
        atomicAdd(&accum[b * 2 + 1], sw4[0] + sw4[1] + sw4[2] + sw4[3]);
        __threadfence();
        int done = atomicAdd(done_cnt, 1);
        if (done == (int)gridDim.x - 1) {
            float s0 = atomicAdd(&accum[0], 0.f);
            float c0 = atomicAdd(&accum[1], 0.f);
            float s1 = atomicAdd(&accum[2], 0.f);
            float c1 = atomicAdd(&accum[3], 0.f);
            float r = s0 / (3.0f * fmaxf(c0, 1.0f))
                    + s1 / (3.0f * fmaxf(c1, 1.0f));
            out[0] = r / (float)NB;
        }
    }
}

// ---------------------------------------------------------------------------
extern "C" void kernel_launch(void* const* d_in, const int* in_sizes, int n_in,
                              void* d_out, int out_size, void* d_ws, size_t ws_size,
                              hipStream_t stream) {
    const float* src_pc = (const float*)d_in[0];   // [2,64,2048,3]
    const float* tgt_pc = (const float*)d_in[1];   // [2,3,64,2048]
    float* out = (float*)d_out;

    char* ws = (char*)d_ws;
    float*  accum   = (float*)ws;                   // 4 floats @ 0
    int*    done    = (int*)(ws + 32);              // 1 int    @ 32
    float*  partial = (float*)(ws + 64);            // 12 planes = 1.5 MB
    uint4*  packed  = (uint4*)(ws + 2097152);       // 1 MB
    float4* tgt4    = (float4*)(ws + 3145728);      // 512 KB

    pack_kernel<<<NQT / 256, 256, 0, stream>>>(tgt_pc, packed, tgt4, (float*)ws);
    knn_mfma<<<NB * NG * 128, 256, 0, stream>>>(src_pc, packed, tgt4, partial);
    merge_final<<<NQT / 256, 256, 0, stream>>>(partial, src_pc, accum, done, out);
}